// Round 1
// baseline (144.080 us; speedup 1.0000x reference)
//
#include <hip/hip_runtime.h>

// B=8, N=256, D=E=G=MID=OUT=128
#define B_ 8
#define N_ 256
#define C_ 128
#define S_ 8   // i-splits

typedef __attribute__((ext_vector_type(4))) float f32x4;
typedef __attribute__((ext_vector_type(8))) short s16x8;

__device__ __forceinline__ unsigned short f2bf(float f) {
  unsigned int u = __builtin_bit_cast(unsigned int, f);
  u += 0x7FFFu + ((u >> 16) & 1u);   // RNE
  return (unsigned short)(u >> 16);
}

// ---------- P0: msg_g = graph @ Wg + bg  (B x C) ----------
__global__ void k_msgg(const float* __restrict__ graph, const float* __restrict__ Wg,
                       const float* __restrict__ bg, float* __restrict__ ws_g) {
  int b = blockIdx.x, m = threadIdx.x;
  float acc = bg[m];
  const float* g = graph + b * C_;
  for (int k = 0; k < C_; ++k) acc += g[k] * Wg[k * C_ + m];
  ws_g[b * C_ + m] = acc;
}

// ---------- P1: c = node@Wn+bn+be+g ; mh = hidden@Wh+bh ; We -> bf16 frags ----------
__global__ void k_prologue(const float* __restrict__ node, const float* __restrict__ hidden,
                           const float* __restrict__ Wn, const float* __restrict__ bn,
                           const float* __restrict__ Wh, const float* __restrict__ bh,
                           const float* __restrict__ We, const float* __restrict__ be,
                           const float* __restrict__ ws_g,
                           float* __restrict__ ws_c, float* __restrict__ ws_mh,
                           short* __restrict__ ws_B) {
  int bid = blockIdx.x, t = threadIdx.x;
  if (bid < 1024) {
    bool isc = bid < 512;
    int row0 = (isc ? bid : bid - 512) * 4;   // row = b*N + n
    const float* src = isc ? node : hidden;
    const float* W   = isc ? Wn : Wh;
    __shared__ float sh[4][C_];
#pragma unroll
    for (int r = 0; r < 4; ++r) sh[r][t] = src[(row0 + r) * C_ + t];
    __syncthreads();
    float init = isc ? (bn[t] + be[t] + ws_g[(row0 >> 8) * C_ + t]) : bh[t];
    float acc[4];
#pragma unroll
    for (int r = 0; r < 4; ++r) acc[r] = init;
    for (int k = 0; k < C_; ++k) {
      float w = W[k * C_ + t];
#pragma unroll
      for (int r = 0; r < 4; ++r) acc[r] += sh[r][k] * w;
    }
    float* dst = isc ? ws_c : ws_mh;
#pragma unroll
    for (int r = 0; r < 4; ++r) dst[(row0 + r) * C_ + t] = acc[r];
  } else {
    // We (128x128 fp32) -> bf16 B-fragments: frag f = kb*8+nb, 64 lanes x 8 elems
    int f = bid - 1024;                // 0..31
    if (t < 64) {
      int kb = f >> 3, nb = f & 7;
      int lr = t & 15, lg = t >> 4;
      s16x8 v;
#pragma unroll
      for (int e = 0; e < 8; ++e)
        v[e] = (short)f2bf(We[(kb * 32 + lg * 8 + e) * C_ + nb * 16 + lr]);
      *reinterpret_cast<s16x8*>(ws_B + (f * 64 + t) * 8) = v;
    }
  }
}

// ---------- Main: fused edge@We + broadcast-add + masked max ----------
// grid 512 WGs x 256 thr. WG -> (b, j16, sp); wave -> ch (col half), s = sp*2 + (w>>1).
// Each wave: 16 j-rows x 64 cols, i in [s*32, s*32+32). Partial max -> pbuf[s].
__global__ __launch_bounds__(256, 2) void k_main(
    const float* __restrict__ edge, const int* __restrict__ adjm,
    const float* __restrict__ ws_c, const float* __restrict__ ws_mh,
    const short* __restrict__ ws_B, float* __restrict__ pbuf) {
  const int lane = threadIdx.x & 63;
  const int w = threadIdx.x >> 6;
  const int wg = blockIdx.x;
  const int sp  = wg & 3;
  const int j16 = (wg >> 2) & 15;
  const int b   = wg >> 6;
  const int ch  = w & 1;
  const int s   = sp * 2 + (w >> 1);
  const int j0 = j16 * 16;
  const int n0 = ch * 64;
  const int i0 = s * 32;
  const int lr = lane & 15;  // A-row / BCD-col
  const int lg = lane >> 4;  // k-group / row-group

  // B fragments (16), held in registers for the whole i loop
  s16x8 bfrag[4][4];
#pragma unroll
  for (int kb = 0; kb < 4; ++kb)
#pragma unroll
    for (int nb = 0; nb < 4; ++nb)
      bfrag[kb][nb] = *reinterpret_cast<const s16x8*>(
          ws_B + ((kb * 8 + ch * 4 + nb) * 64 + lane) * 8);

  // c fragment (per output element), loaded once
  float cf[4][4];
#pragma unroll
  for (int nb = 0; nb < 4; ++nb)
#pragma unroll
    for (int r = 0; r < 4; ++r)
      cf[nb][r] = ws_c[(b * N_ + j0 + lg * 4 + r) * C_ + n0 + nb * 16 + lr];

  f32x4 mx[4];
#pragma unroll
  for (int nb = 0; nb < 4; ++nb)
#pragma unroll
    for (int r = 0; r < 4; ++r) mx[nb][r] = -INFINITY;

  const float* erow  = edge + ((b * N_ + i0) * N_ + j0 + lr) * C_ + lg * 8;
  const float* mhrow = ws_mh + (b * N_ + i0) * C_ + n0 + lr;
  const int*   arow  = adjm + (b * N_ + i0) * N_ + j0 + lg * 4;

  for (int ii = 0; ii < 32; ++ii) {
    // A fragments: 16 rows x 128 k, fp32 -> bf16
    s16x8 af[4];
#pragma unroll
    for (int kb = 0; kb < 4; ++kb) {
      f32x4 lo = *reinterpret_cast<const f32x4*>(erow + kb * 32);
      f32x4 hi = *reinterpret_cast<const f32x4*>(erow + kb * 32 + 4);
      s16x8 a;
#pragma unroll
      for (int e = 0; e < 4; ++e) { a[e] = (short)f2bf(lo[e]); a[e + 4] = (short)f2bf(hi[e]); }
      af[kb] = a;
    }
    float mh[4];
#pragma unroll
    for (int nb = 0; nb < 4; ++nb) mh[nb] = mhrow[nb * 16];
    int4 a4 = *reinterpret_cast<const int4*>(arow);
    float adjf[4] = {(float)a4.x, (float)a4.y, (float)a4.z, (float)a4.w};

#pragma unroll
    for (int nb = 0; nb < 4; ++nb) {
      f32x4 acc;
#pragma unroll
      for (int r = 0; r < 4; ++r) acc[r] = cf[nb][r] + mh[nb];  // C-init = c + mh
#pragma unroll
      for (int kb = 0; kb < 4; ++kb)
        acc = __builtin_amdgcn_mfma_f32_16x16x32_bf16(af[kb], bfrag[kb][nb], acc, 0, 0, 0);
#pragma unroll
      for (int r = 0; r < 4; ++r) mx[nb][r] = fmaxf(mx[nb][r], adjf[r] * acc[r]);
    }
    erow  += N_ * C_;
    mhrow += C_;
    arow  += N_;
  }

  float* prow = pbuf + ((s * B_ + b) * N_ + j0 + lg * 4) * C_ + n0 + lr;
#pragma unroll
  for (int nb = 0; nb < 4; ++nb)
#pragma unroll
    for (int r = 0; r < 4; ++r)
      prow[r * C_ + nb * 16] = mx[nb][r];
}

// ---------- Epilogue: S-max + node@Wo1 + hidden@Wo2 + msgs@Wo3 ----------
__global__ void k_epilogue(const float* __restrict__ node, const float* __restrict__ hidden,
                           const float* __restrict__ Wo1, const float* __restrict__ bo1,
                           const float* __restrict__ Wo2, const float* __restrict__ bo2,
                           const float* __restrict__ Wo3, const float* __restrict__ bo3,
                           const float* __restrict__ pbuf, float* __restrict__ out) {
  int bid = blockIdx.x, t = threadIdx.x;
  int row0 = bid * 4;
  __shared__ float shn[4][C_], shh[4][C_], shm[4][C_];
#pragma unroll
  for (int r = 0; r < 4; ++r) {
    shn[r][t] = node[(row0 + r) * C_ + t];
    shh[r][t] = hidden[(row0 + r) * C_ + t];
    float mv = -INFINITY;
    for (int s = 0; s < S_; ++s)
      mv = fmaxf(mv, pbuf[(s * (B_ * N_) + row0 + r) * C_ + t]);
    shm[r][t] = mv;
  }
  __syncthreads();
  float init = bo1[t] + bo2[t] + bo3[t];
  float acc[4];
#pragma unroll
  for (int r = 0; r < 4; ++r) acc[r] = init;
  for (int k = 0; k < C_; ++k) {
    float w1 = Wo1[k * C_ + t], w2 = Wo2[k * C_ + t], w3 = Wo3[k * C_ + t];
#pragma unroll
    for (int r = 0; r < 4; ++r)
      acc[r] += shn[r][k] * w1 + shh[r][k] * w2 + shm[r][k] * w3;
  }
#pragma unroll
  for (int r = 0; r < 4; ++r) out[(row0 + r) * C_ + t] = acc[r];
}

extern "C" void kernel_launch(void* const* d_in, const int* in_sizes, int n_in,
                              void* d_out, int out_size, void* d_ws, size_t ws_size,
                              hipStream_t stream) {
  const float* node   = (const float*)d_in[0];
  const float* edge   = (const float*)d_in[1];
  const float* graph  = (const float*)d_in[2];
  const int*   adjm   = (const int*)d_in[3];
  const float* hidden = (const float*)d_in[4];
  const float* Wn = (const float*)d_in[5];  const float* bn = (const float*)d_in[6];
  const float* Wh = (const float*)d_in[7];  const float* bh = (const float*)d_in[8];
  const float* We = (const float*)d_in[9];  const float* be = (const float*)d_in[10];
  const float* Wg = (const float*)d_in[11]; const float* bg = (const float*)d_in[12];
  const float* Wo1 = (const float*)d_in[13]; const float* bo1 = (const float*)d_in[14];
  const float* Wo2 = (const float*)d_in[15]; const float* bo2 = (const float*)d_in[16];
  const float* Wo3 = (const float*)d_in[17]; const float* bo3 = (const float*)d_in[18];
  float* out = (float*)d_out;

  char* ws = (char*)d_ws;
  float* ws_c  = (float*)ws;                              // 1 MB
  float* ws_mh = (float*)(ws + (1u << 20));               // 1 MB
  float* ws_g  = (float*)(ws + (2u << 20));               // 4 KB
  short* ws_B  = (short*)(ws + (2u << 20) + (1u << 16));  // 32 KB bf16 frags
  float* pbuf  = (float*)(ws + (4u << 20));               // 8 MB partials

  k_msgg<<<8, 128, 0, stream>>>(graph, Wg, bg, ws_g);
  k_prologue<<<1056, 128, 0, stream>>>(node, hidden, Wn, bn, Wh, bh, We, be,
                                       ws_g, ws_c, ws_mh, ws_B);
  k_main<<<512, 256, 0, stream>>>(edge, adjm, ws_c, ws_mh, ws_B, pbuf);
  k_epilogue<<<512, 128, 0, stream>>>(node, hidden, Wo1, bo1, Wo2, bo2, Wo3, bo3,
                                      pbuf, out);
}

// Round 3
// 124.345 us; speedup vs baseline: 1.1587x; 1.1587x over previous
//
#include <hip/hip_runtime.h>
#include <hip/hip_bf16.h>

// B=8, N=256, D=E=G=MID=OUT=128
#define B_ 8
#define N_ 256
#define C_ 128
#define S_ 8   // i-splits

typedef __attribute__((ext_vector_type(4))) float f32x4;
typedef __attribute__((ext_vector_type(8))) short s16x8;

__device__ __forceinline__ unsigned short f2bf(float f) {
  unsigned int u = __builtin_bit_cast(unsigned int, f);
  u += 0x7FFFu + ((u >> 16) & 1u);   // RNE
  return (unsigned short)(u >> 16);
}

__device__ __forceinline__ unsigned int pk2(float a, float b) {
  __hip_bfloat162 h = __float22bfloat162_rn(make_float2(a, b));
  unsigned int u;
  __builtin_memcpy(&u, &h, 4);
  return u;
}

// packed f32x8 -> bf16x8 via v_cvt_pk_bf16_f32 (compiler-generated from _rn casts)
__device__ __forceinline__ s16x8 cvt8(f32x4 lo, f32x4 hi) {
  union { unsigned int u[4]; s16x8 s; } r;
  r.u[0] = pk2(lo[0], lo[1]);
  r.u[1] = pk2(lo[2], lo[3]);
  r.u[2] = pk2(hi[0], hi[1]);
  r.u[3] = pk2(hi[2], hi[3]);
  return r.s;
}

// ---------- P: c = node@Wn+bn+be+(graph@Wg+bg) ; mh = hidden@Wh+bh ----------
// 512 blocks x 128 thr; blocks 0..255 -> c (8 rows each), 256..511 -> mh
__global__ void k_pro(const float* __restrict__ node, const float* __restrict__ hidden,
                      const float* __restrict__ graph,
                      const float* __restrict__ Wn, const float* __restrict__ bn,
                      const float* __restrict__ Wh, const float* __restrict__ bh,
                      const float* __restrict__ be,
                      const float* __restrict__ Wg, const float* __restrict__ bg,
                      float* __restrict__ ws_c, float* __restrict__ ws_mh) {
  int bid = blockIdx.x, t = threadIdx.x;
  bool isc = bid < 256;
  int row0 = (isc ? bid : bid - 256) * 8;     // row = b*N + n
  const float* src = isc ? node : hidden;
  const float* W   = isc ? Wn : Wh;
  __shared__ float sh[8][C_];
#pragma unroll
  for (int r = 0; r < 8; ++r) sh[r][t] = src[(row0 + r) * C_ + t];
  __syncthreads();
  float init;
  if (isc) {
    int b = row0 >> 8;
    float g = bg[t];
    const float* gr = graph + b * C_;
    for (int k = 0; k < C_; ++k) g += gr[k] * Wg[k * C_ + t];
    init = bn[t] + be[t] + g;
  } else {
    init = bh[t];
  }
  float acc[8];
#pragma unroll
  for (int r = 0; r < 8; ++r) acc[r] = init;
  for (int k = 0; k < C_; ++k) {
    float w = W[k * C_ + t];
#pragma unroll
    for (int r = 0; r < 8; ++r) acc[r] += sh[r][k] * w;
  }
  float* dst = isc ? ws_c : ws_mh;
#pragma unroll
  for (int r = 0; r < 8; ++r) dst[(row0 + r) * C_ + t] = acc[r];
}

// ---------- Main: fused edge@We + broadcast-add + masked max ----------
// grid 512 WGs x 256 thr. WG -> (b, j16, sp); wave -> ch (col half), s = sp*2 + (w>>1).
// Each wave: 16 j-rows x 64 cols, i in [s*32, s*32+32). Register-double-buffered loads.
__global__ __launch_bounds__(256, 2) void k_main(
    const float* __restrict__ edge, const int* __restrict__ adjm,
    const float* __restrict__ We,
    const float* __restrict__ ws_c, const float* __restrict__ ws_mh,
    float* __restrict__ pbuf) {
  const int lane = threadIdx.x & 63;
  const int w = threadIdx.x >> 6;
  const int wg = blockIdx.x;
  const int sp  = wg & 3;
  const int j16 = (wg >> 2) & 15;
  const int b   = wg >> 6;
  const int ch  = w & 1;
  const int s   = sp * 2 + (w >> 1);
  const int j0 = j16 * 16;
  const int n0 = ch * 64;
  const int i0 = s * 32;
  const int lr = lane & 15;  // A-row / BCD-col
  const int lg = lane >> 4;  // k-group / row-group

  // B fragments gathered straight from We (64 KB, L2-resident), one-time
  s16x8 bfrag[4][4];
#pragma unroll
  for (int kb = 0; kb < 4; ++kb)
#pragma unroll
    for (int nb = 0; nb < 4; ++nb) {
      int col = n0 + nb * 16 + lr;
      s16x8 v;
#pragma unroll
      for (int e = 0; e < 8; ++e)
        v[e] = (short)f2bf(We[(kb * 32 + lg * 8 + e) * C_ + col]);
      bfrag[kb][nb] = v;
    }

  // c fragment (i-invariant part of output element), loaded once
  float cf[4][4];
#pragma unroll
  for (int nb = 0; nb < 4; ++nb)
#pragma unroll
    for (int r = 0; r < 4; ++r)
      cf[nb][r] = ws_c[(b * N_ + j0 + lg * 4 + r) * C_ + n0 + nb * 16 + lr];

  f32x4 mx[4];
#pragma unroll
  for (int nb = 0; nb < 4; ++nb)
#pragma unroll
    for (int r = 0; r < 4; ++r) mx[nb][r] = -INFINITY;

  const float* erow  = edge + ((b * N_ + i0) * N_ + j0 + lr) * C_ + lg * 8;
  const float* mhrow = ws_mh + (b * N_ + i0) * C_ + n0 + lr;
  const int*   arow  = adjm + (b * N_ + i0) * N_ + j0 + lg * 4;

  // prefetch registers (double buffer)
  f32x4 plo[4], phi[4];
  float pmh[4];
  int4  pa4;
#pragma unroll
  for (int kb = 0; kb < 4; ++kb) {
    plo[kb] = *reinterpret_cast<const f32x4*>(erow + kb * 32);
    phi[kb] = *reinterpret_cast<const f32x4*>(erow + kb * 32 + 4);
  }
#pragma unroll
  for (int nb = 0; nb < 4; ++nb) pmh[nb] = mhrow[nb * 16];
  pa4 = *reinterpret_cast<const int4*>(arow);

  for (int ii = 0; ii < 32; ++ii) {
    // consume current
    s16x8 af[4];
#pragma unroll
    for (int kb = 0; kb < 4; ++kb) af[kb] = cvt8(plo[kb], phi[kb]);
    float mhv[4] = {pmh[0], pmh[1], pmh[2], pmh[3]};
    float adjf[4] = {(float)pa4.x, (float)pa4.y, (float)pa4.z, (float)pa4.w};

    // issue next i's loads; they fly during the MFMA block below
    erow  += N_ * C_;
    mhrow += C_;
    arow  += N_;
    if (ii < 31) {
#pragma unroll
      for (int kb = 0; kb < 4; ++kb) {
        plo[kb] = *reinterpret_cast<const f32x4*>(erow + kb * 32);
        phi[kb] = *reinterpret_cast<const f32x4*>(erow + kb * 32 + 4);
      }
#pragma unroll
      for (int nb = 0; nb < 4; ++nb) pmh[nb] = mhrow[nb * 16];
      pa4 = *reinterpret_cast<const int4*>(arow);
    }

#pragma unroll
    for (int nb = 0; nb < 4; ++nb) {
      f32x4 acc;
#pragma unroll
      for (int r = 0; r < 4; ++r) acc[r] = cf[nb][r] + mhv[nb];  // C-init = c + mh
#pragma unroll
      for (int kb = 0; kb < 4; ++kb)
        acc = __builtin_amdgcn_mfma_f32_16x16x32_bf16(af[kb], bfrag[kb][nb], acc, 0, 0, 0);
#pragma unroll
      for (int r = 0; r < 4; ++r) mx[nb][r] = fmaxf(mx[nb][r], adjf[r] * acc[r]);
    }
  }

  float* prow = pbuf + ((s * B_ + b) * N_ + j0 + lg * 4) * C_ + n0 + lr;
#pragma unroll
  for (int nb = 0; nb < 4; ++nb)
#pragma unroll
    for (int r = 0; r < 4; ++r)
      prow[r * C_ + nb * 16] = mx[nb][r];
}

// ---------- Epilogue: S-max + node@Wo1 + hidden@Wo2 + msgs@Wo3 ----------
// 256 blocks x 256 thr; block handles 8 rows, thread (col = t&127, half = t>>7) does 4 rows
__global__ void k_epi(const float* __restrict__ node, const float* __restrict__ hidden,
                      const float* __restrict__ Wo1, const float* __restrict__ bo1,
                      const float* __restrict__ Wo2, const float* __restrict__ bo2,
                      const float* __restrict__ Wo3, const float* __restrict__ bo3,
                      const float* __restrict__ pbuf, float* __restrict__ out) {
  int row0 = blockIdx.x * 8;
  int col = threadIdx.x & 127;
  int half = threadIdx.x >> 7;
  __shared__ float shn[8][C_], shh[8][C_], shm[8][C_];
#pragma unroll
  for (int r = 0; r < 4; ++r) {
    int rr = half * 4 + r;
    shn[rr][col] = node[(row0 + rr) * C_ + col];
    shh[rr][col] = hidden[(row0 + rr) * C_ + col];
    float mv = -INFINITY;
#pragma unroll
    for (int s = 0; s < S_; ++s)
      mv = fmaxf(mv, pbuf[(s * (B_ * N_) + row0 + rr) * C_ + col]);
    shm[rr][col] = mv;
  }
  __syncthreads();
  float init = bo1[col] + bo2[col] + bo3[col];
  float acc[4];
#pragma unroll
  for (int r = 0; r < 4; ++r) acc[r] = init;
  for (int k = 0; k < C_; ++k) {
    float w1 = Wo1[k * C_ + col], w2 = Wo2[k * C_ + col], w3 = Wo3[k * C_ + col];
#pragma unroll
    for (int r = 0; r < 4; ++r) {
      int rr = half * 4 + r;
      acc[r] += shn[rr][k] * w1 + shh[rr][k] * w2 + shm[rr][k] * w3;
    }
  }
#pragma unroll
  for (int r = 0; r < 4; ++r)
    out[(row0 + half * 4 + r) * C_ + col] = acc[r];
}

extern "C" void kernel_launch(void* const* d_in, const int* in_sizes, int n_in,
                              void* d_out, int out_size, void* d_ws, size_t ws_size,
                              hipStream_t stream) {
  const float* node   = (const float*)d_in[0];
  const float* edge   = (const float*)d_in[1];
  const float* graph  = (const float*)d_in[2];
  const int*   adjm   = (const int*)d_in[3];
  const float* hidden = (const float*)d_in[4];
  const float* Wn = (const float*)d_in[5];  const float* bn = (const float*)d_in[6];
  const float* Wh = (const float*)d_in[7];  const float* bh = (const float*)d_in[8];
  const float* We = (const float*)d_in[9];  const float* be = (const float*)d_in[10];
  const float* Wg = (const float*)d_in[11]; const float* bg = (const float*)d_in[12];
  const float* Wo1 = (const float*)d_in[13]; const float* bo1 = (const float*)d_in[14];
  const float* Wo2 = (const float*)d_in[15]; const float* bo2 = (const float*)d_in[16];
  const float* Wo3 = (const float*)d_in[17]; const float* bo3 = (const float*)d_in[18];
  float* out = (float*)d_out;

  char* ws = (char*)d_ws;
  float* ws_c  = (float*)ws;                 // 1 MB
  float* ws_mh = (float*)(ws + (1u << 20));  // 1 MB
  float* pbuf  = (float*)(ws + (2u << 20));  // 8 MB partials

  k_pro<<<512, 128, 0, stream>>>(node, hidden, graph, Wn, bn, Wh, bh, be, Wg, bg,
                                 ws_c, ws_mh);
  k_main<<<512, 256, 0, stream>>>(edge, adjm, We, ws_c, ws_mh, pbuf);
  k_epi<<<256, 256, 0, stream>>>(node, hidden, Wo1, bo1, Wo2, bo2, Wo3, bo3,
                                 pbuf, out);
}

// Round 4
// 118.652 us; speedup vs baseline: 1.2143x; 1.0480x over previous
//
#include <hip/hip_runtime.h>
#include <hip/hip_bf16.h>

// B=8, N=256, D=E=G=MID=OUT=128
#define B_ 8
#define N_ 256
#define C_ 128
#define S_ 8   // i-splits

typedef __attribute__((ext_vector_type(4))) float f32x4;
typedef __attribute__((ext_vector_type(8))) short s16x8;

__device__ __forceinline__ unsigned short f2bf(float f) {
  unsigned int u = __builtin_bit_cast(unsigned int, f);
  u += 0x7FFFu + ((u >> 16) & 1u);   // RNE
  return (unsigned short)(u >> 16);
}

__device__ __forceinline__ unsigned int pk2(float a, float b) {
  __hip_bfloat162 h = __float22bfloat162_rn(make_float2(a, b));
  unsigned int u;
  __builtin_memcpy(&u, &h, 4);
  return u;
}

// packed f32x8 -> bf16x8 via v_cvt_pk_bf16_f32
__device__ __forceinline__ s16x8 cvt8(f32x4 lo, f32x4 hi) {
  union { unsigned int u[4]; s16x8 s; } r;
  r.u[0] = pk2(lo[0], lo[1]);
  r.u[1] = pk2(lo[2], lo[3]);
  r.u[2] = pk2(hi[0], hi[1]);
  r.u[3] = pk2(hi[2], hi[3]);
  return r.s;
}

// ---------- P: c = node@Wn+bn+be+(graph@Wg+bg) ; mh = hidden@Wh+bh ----------
// 512 blocks x 128 thr; blocks 0..255 -> c (8 rows each), 256..511 -> mh
__global__ void k_pro(const float* __restrict__ node, const float* __restrict__ hidden,
                      const float* __restrict__ graph,
                      const float* __restrict__ Wn, const float* __restrict__ bn,
                      const float* __restrict__ Wh, const float* __restrict__ bh,
                      const float* __restrict__ be,
                      const float* __restrict__ Wg, const float* __restrict__ bg,
                      float* __restrict__ ws_c, float* __restrict__ ws_mh) {
  int bid = blockIdx.x, t = threadIdx.x;
  bool isc = bid < 256;
  int row0 = (isc ? bid : bid - 256) * 8;     // row = b*N + n
  const float* src = isc ? node : hidden;
  const float* W   = isc ? Wn : Wh;
  __shared__ float sh[8][C_];
#pragma unroll
  for (int r = 0; r < 8; ++r) sh[r][t] = src[(row0 + r) * C_ + t];
  __syncthreads();
  float init;
  if (isc) {
    int b = row0 >> 8;
    float g = bg[t];
    const float* gr = graph + b * C_;
    for (int k = 0; k < C_; k += 8) {
      float wv[8];
#pragma unroll
      for (int u = 0; u < 8; ++u) wv[u] = Wg[(k + u) * C_ + t];
#pragma unroll
      for (int u = 0; u < 8; ++u) g += gr[k + u] * wv[u];
    }
    init = bn[t] + be[t] + g;
  } else {
    init = bh[t];
  }
  float acc[8];
#pragma unroll
  for (int r = 0; r < 8; ++r) acc[r] = init;
  for (int k = 0; k < C_; k += 8) {
    float wv[8];
#pragma unroll
    for (int u = 0; u < 8; ++u) wv[u] = W[(k + u) * C_ + t];
#pragma unroll
    for (int u = 0; u < 8; ++u)
#pragma unroll
      for (int r = 0; r < 8; ++r) acc[r] += sh[r][k + u] * wv[u];
  }
  float* dst = isc ? ws_c : ws_mh;
#pragma unroll
  for (int r = 0; r < 8; ++r) dst[(row0 + r) * C_ + t] = acc[r];
}

// ---------- Main: fused edge@We + broadcast-add + masked max ----------
// grid 512 WGs x 256 thr. WG -> (b, j16, sp); wave -> ch (col half), s = sp*2 + (w>>1).
// Each wave: 16 j-rows x 64 cols, i in [s*32, s*32+32). Register-double-buffered loads.
__global__ __launch_bounds__(256, 3) void k_main(
    const float* __restrict__ edge, const int* __restrict__ adjm,
    const float* __restrict__ We,
    const float* __restrict__ ws_c, const float* __restrict__ ws_mh,
    float* __restrict__ pbuf) {
  const int lane = threadIdx.x & 63;
  const int w = threadIdx.x >> 6;
  const int wg = blockIdx.x;
  const int sp  = wg & 3;
  const int j16 = (wg >> 2) & 15;
  const int b   = wg >> 6;
  const int ch  = w & 1;
  const int s   = sp * 2 + (w >> 1);
  const int j0 = j16 * 16;
  const int n0 = ch * 64;
  const int i0 = s * 32;
  const int lr = lane & 15;  // A-row / BCD-col
  const int lg = lane >> 4;  // k-group / row-group

  // B fragments gathered straight from We (64 KB, L2-resident), one-time
  s16x8 bfrag[4][4];
#pragma unroll
  for (int kb = 0; kb < 4; ++kb)
#pragma unroll
    for (int nb = 0; nb < 4; ++nb) {
      int col = n0 + nb * 16 + lr;
      s16x8 v;
#pragma unroll
      for (int e = 0; e < 8; ++e)
        v[e] = (short)f2bf(We[(kb * 32 + lg * 8 + e) * C_ + col]);
      bfrag[kb][nb] = v;
    }

  // c fragment (i-invariant part of output element), loaded once
  float cf[4][4];
#pragma unroll
  for (int nb = 0; nb < 4; ++nb)
#pragma unroll
    for (int r = 0; r < 4; ++r)
      cf[nb][r] = ws_c[(b * N_ + j0 + lg * 4 + r) * C_ + n0 + nb * 16 + lr];

  f32x4 mx[4];
#pragma unroll
  for (int nb = 0; nb < 4; ++nb)
#pragma unroll
    for (int r = 0; r < 4; ++r) mx[nb][r] = -INFINITY;

  const float* erow  = edge + ((b * N_ + i0) * N_ + j0 + lr) * C_ + lg * 8;
  const float* mhrow = ws_mh + (b * N_ + i0) * C_ + n0 + lr;
  const int*   arow  = adjm + (b * N_ + i0) * N_ + j0 + lg * 4;

  // prefetch registers (double buffer)
  f32x4 plo[4], phi[4];
  float pmh[4];
  int4  pa4;
#pragma unroll
  for (int kb = 0; kb < 4; ++kb) {
    plo[kb] = *reinterpret_cast<const f32x4*>(erow + kb * 32);
    phi[kb] = *reinterpret_cast<const f32x4*>(erow + kb * 32 + 4);
  }
#pragma unroll
  for (int nb = 0; nb < 4; ++nb) pmh[nb] = mhrow[nb * 16];
  pa4 = *reinterpret_cast<const int4*>(arow);

  for (int ii = 0; ii < 32; ++ii) {
    // consume current
    s16x8 af[4];
#pragma unroll
    for (int kb = 0; kb < 4; ++kb) af[kb] = cvt8(plo[kb], phi[kb]);
    float mhv[4] = {pmh[0], pmh[1], pmh[2], pmh[3]};
    float adjf[4] = {(float)pa4.x, (float)pa4.y, (float)pa4.z, (float)pa4.w};

    // issue next i's loads; they fly during the MFMA block below
    erow  += N_ * C_;
    mhrow += C_;
    arow  += N_;
    if (ii < 31) {
#pragma unroll
      for (int kb = 0; kb < 4; ++kb) {
        plo[kb] = *reinterpret_cast<const f32x4*>(erow + kb * 32);
        phi[kb] = *reinterpret_cast<const f32x4*>(erow + kb * 32 + 4);
      }
#pragma unroll
      for (int nb = 0; nb < 4; ++nb) pmh[nb] = mhrow[nb * 16];
      pa4 = *reinterpret_cast<const int4*>(arow);
    }

#pragma unroll
    for (int nb = 0; nb < 4; ++nb) {
      f32x4 acc;
#pragma unroll
      for (int r = 0; r < 4; ++r) acc[r] = cf[nb][r] + mhv[nb];  // C-init = c + mh
#pragma unroll
      for (int kb = 0; kb < 4; ++kb)
        acc = __builtin_amdgcn_mfma_f32_16x16x32_bf16(af[kb], bfrag[kb][nb], acc, 0, 0, 0);
#pragma unroll
      for (int r = 0; r < 4; ++r) mx[nb][r] = fmaxf(mx[nb][r], adjf[r] * acc[r]);
    }
  }

  float* prow = pbuf + ((s * B_ + b) * N_ + j0 + lg * 4) * C_ + n0 + lr;
#pragma unroll
  for (int nb = 0; nb < 4; ++nb)
#pragma unroll
    for (int r = 0; r < 4; ++r)
      prow[r * C_ + nb * 16] = mx[nb][r];
}

// ---------- Epilogue: S-max + node@Wo1 + hidden@Wo2 + msgs@Wo3 ----------
// 256 blocks x 256 thr; block handles 8 rows, thread (col = t&127, half = t>>7) does 4 rows
__global__ void k_epi(const float* __restrict__ node, const float* __restrict__ hidden,
                      const float* __restrict__ Wo1, const float* __restrict__ bo1,
                      const float* __restrict__ Wo2, const float* __restrict__ bo2,
                      const float* __restrict__ Wo3, const float* __restrict__ bo3,
                      const float* __restrict__ pbuf, float* __restrict__ out) {
  int row0 = blockIdx.x * 8;
  int col = threadIdx.x & 127;
  int half = threadIdx.x >> 7;
  __shared__ float shn[8][C_], shh[8][C_], shm[8][C_];
#pragma unroll
  for (int r = 0; r < 4; ++r) {
    int rr = half * 4 + r;
    shn[rr][col] = node[(row0 + rr) * C_ + col];
    shh[rr][col] = hidden[(row0 + rr) * C_ + col];
    float mv = -INFINITY;
#pragma unroll
    for (int s = 0; s < S_; ++s)
      mv = fmaxf(mv, pbuf[(s * (B_ * N_) + row0 + rr) * C_ + col]);
    shm[rr][col] = mv;
  }
  __syncthreads();
  float init = bo1[col] + bo2[col] + bo3[col];
  float acc[4];
#pragma unroll
  for (int r = 0; r < 4; ++r) acc[r] = init;
  for (int k = 0; k < C_; k += 8) {
    float wv1[8], wv2[8], wv3[8];
#pragma unroll
    for (int u = 0; u < 8; ++u) {
      wv1[u] = Wo1[(k + u) * C_ + col];
      wv2[u] = Wo2[(k + u) * C_ + col];
      wv3[u] = Wo3[(k + u) * C_ + col];
    }
#pragma unroll
    for (int u = 0; u < 8; ++u)
#pragma unroll
      for (int r = 0; r < 4; ++r) {
        int rr = half * 4 + r;
        acc[r] += shn[rr][k + u] * wv1[u] + shh[rr][k + u] * wv2[u] + shm[rr][k + u] * wv3[u];
      }
  }
#pragma unroll
  for (int r = 0; r < 4; ++r)
    out[(row0 + half * 4 + r) * C_ + col] = acc[r];
}

extern "C" void kernel_launch(void* const* d_in, const int* in_sizes, int n_in,
                              void* d_out, int out_size, void* d_ws, size_t ws_size,
                              hipStream_t stream) {
  const float* node   = (const float*)d_in[0];
  const float* edge   = (const float*)d_in[1];
  const float* graph  = (const float*)d_in[2];
  const int*   adjm   = (const int*)d_in[3];
  const float* hidden = (const float*)d_in[4];
  const float* Wn = (const float*)d_in[5];  const float* bn = (const float*)d_in[6];
  const float* Wh = (const float*)d_in[7];  const float* bh = (const float*)d_in[8];
  const float* We = (const float*)d_in[9];  const float* be = (const float*)d_in[10];
  const float* Wg = (const float*)d_in[11]; const float* bg = (const float*)d_in[12];
  const float* Wo1 = (const float*)d_in[13]; const float* bo1 = (const float*)d_in[14];
  const float* Wo2 = (const float*)d_in[15]; const float* bo2 = (const float*)d_in[16];
  const float* Wo3 = (const float*)d_in[17]; const float* bo3 = (const float*)d_in[18];
  float* out = (float*)d_out;

  char* ws = (char*)d_ws;
  float* ws_c  = (float*)ws;                 // 1 MB
  float* ws_mh = (float*)(ws + (1u << 20));  // 1 MB
  float* pbuf  = (float*)(ws + (2u << 20));  // 8 MB partials

  k_pro<<<512, 128, 0, stream>>>(node, hidden, graph, Wn, bn, Wh, bh, be, Wg, bg,
                                 ws_c, ws_mh);
  k_main<<<512, 256, 0, stream>>>(edge, adjm, We, ws_c, ws_mh, pbuf);
  k_epi<<<256, 256, 0, stream>>>(node, hidden, Wo1, bo1, Wo2, bo2, Wo3, bo3,
                                 pbuf, out);
}

// Round 5
// 97.681 us; speedup vs baseline: 1.4750x; 1.2147x over previous
//
#include <hip/hip_runtime.h>
#include <hip/hip_bf16.h>

// B=8, N=256, D=E=G=MID=OUT=128
#define B_ 8
#define N_ 256
#define C_ 128
#define S_ 8       // i-splits
#define CHUNK 8192 // 16 rows x 128 f32 = 8KB staged per pair-step
#define STEPB (N_ * C_ * 4)

typedef __attribute__((ext_vector_type(4))) float f32x4;
typedef __attribute__((ext_vector_type(8))) short s16x8;

typedef __attribute__((address_space(1))) const void gas_void;
typedef __attribute__((address_space(3))) void las_void;

__device__ __forceinline__ unsigned short f2bf(float f) {
  unsigned int u = __builtin_bit_cast(unsigned int, f);
  u += 0x7FFFu + ((u >> 16) & 1u);   // RNE
  return (unsigned short)(u >> 16);
}

__device__ __forceinline__ unsigned int pk2(float a, float b) {
  __hip_bfloat162 h = __float22bfloat162_rn(make_float2(a, b));
  unsigned int u;
  __builtin_memcpy(&u, &h, 4);
  return u;
}

__device__ __forceinline__ s16x8 cvt8(f32x4 lo, f32x4 hi) {
  union { unsigned int u[4]; s16x8 s; } r;
  r.u[0] = pk2(lo[0], lo[1]);
  r.u[1] = pk2(lo[2], lo[3]);
  r.u[2] = pk2(hi[0], hi[1]);
  r.u[3] = pk2(hi[2], hi[3]);
  return r.s;
}

// ---------- P: c = node@Wn+bn+be+(graph@Wg+bg) ; mh = hidden@Wh+bh ----------
__global__ void k_pro(const float* __restrict__ node, const float* __restrict__ hidden,
                      const float* __restrict__ graph,
                      const float* __restrict__ Wn, const float* __restrict__ bn,
                      const float* __restrict__ Wh, const float* __restrict__ bh,
                      const float* __restrict__ be,
                      const float* __restrict__ Wg, const float* __restrict__ bg,
                      float* __restrict__ ws_c, float* __restrict__ ws_mh) {
  int bid = blockIdx.x, t = threadIdx.x;
  bool isc = bid < 256;
  int row0 = (isc ? bid : bid - 256) * 8;     // row = b*N + n
  const float* src = isc ? node : hidden;
  const float* W   = isc ? Wn : Wh;
  __shared__ float sh[8][C_];
#pragma unroll
  for (int r = 0; r < 8; ++r) sh[r][t] = src[(row0 + r) * C_ + t];
  __syncthreads();
  float init;
  if (isc) {
    int b = row0 >> 8;
    float g = bg[t];
    const float* gr = graph + b * C_;
    for (int k = 0; k < C_; k += 8) {
      float wv[8];
#pragma unroll
      for (int u = 0; u < 8; ++u) wv[u] = Wg[(k + u) * C_ + t];
#pragma unroll
      for (int u = 0; u < 8; ++u) g += gr[k + u] * wv[u];
    }
    init = bn[t] + be[t] + g;
  } else {
    init = bh[t];
  }
  float acc[8];
#pragma unroll
  for (int r = 0; r < 8; ++r) acc[r] = init;
  for (int k = 0; k < C_; k += 8) {
    float wv[8];
#pragma unroll
    for (int u = 0; u < 8; ++u) wv[u] = W[(k + u) * C_ + t];
#pragma unroll
    for (int u = 0; u < 8; ++u)
#pragma unroll
      for (int r = 0; r < 8; ++r) acc[r] += sh[r][k + u] * wv[u];
  }
  float* dst = isc ? ws_c : ws_mh;
#pragma unroll
  for (int r = 0; r < 8; ++r) dst[(row0 + r) * C_ + t] = acc[r];
}

// ---------- Main: fused edge@We + broadcast-add + masked max ----------
// 512 WGs x 256 thr. WG -> (b, j16, sp). Wave pair p handles s = sp*2+p (i-chunk of 32);
// within a pair, ch = col half. Pair stages 8KB edge chunk (16 j-rows x 128 f32) into LDS,
// double-buffered, counted vmcnt(9), raw s_barrier (no implicit vmcnt(0) drain),
// XOR-swizzled layout (linear DMA dest + inverse-swizzled global src + swizzled ds_read).
__global__ __launch_bounds__(256, 2) void k_main(
    const float* __restrict__ edge, const int* __restrict__ adjm,
    const float* __restrict__ We,
    const float* __restrict__ ws_c, const float* __restrict__ ws_mh,
    float* __restrict__ pbuf) {
  __shared__ __align__(16) float smemf[2 * 2 * CHUNK / 4];  // 32 KB
  char* smem = (char*)smemf;
  const int lane = threadIdx.x & 63;
  const int w = threadIdx.x >> 6;
  const int pair = w >> 1;
  const int ch = w & 1;
  const int wg = blockIdx.x;
  const int sp  = wg & 3;
  const int j16 = (wg >> 2) & 15;
  const int b   = wg >> 6;
  const int s   = sp * 2 + pair;
  const int j0 = j16 * 16;
  const int n0 = ch * 64;
  const int i0 = s * 32;
  const int lr = lane & 15;  // A-row / BCD-col
  const int lg = lane >> 4;  // k-group / row-group

  char* mybuf = smem + pair * (2 * CHUNK);

  // B fragments gathered from We (64 KB, L2-resident), one-time
  s16x8 bfrag[4][4];
#pragma unroll
  for (int kb = 0; kb < 4; ++kb)
#pragma unroll
    for (int nb = 0; nb < 4; ++nb) {
      int col = n0 + nb * 16 + lr;
      s16x8 v;
#pragma unroll
      for (int e = 0; e < 8; ++e)
        v[e] = (short)f2bf(We[(kb * 32 + lg * 8 + e) * C_ + col]);
      bfrag[kb][nb] = v;
    }

  // c fragment (i-invariant part of output), loaded once
  float cf[4][4];
#pragma unroll
  for (int nb = 0; nb < 4; ++nb)
#pragma unroll
    for (int r = 0; r < 4; ++r)
      cf[nb][r] = ws_c[(b * N_ + j0 + lg * 4 + r) * C_ + n0 + nb * 16 + lr];

  f32x4 mx[4];
#pragma unroll
  for (int nb = 0; nb < 4; ++nb)
#pragma unroll
    for (int r = 0; r < 4; ++r) mx[nb][r] = -INFINITY;

  const char* gedge = (const char*)(edge + ((size_t)(b * N_ + i0) * N_ + j0) * C_);
  const float* mhbase = ws_mh + ((size_t)(b * N_) + i0) * C_ + n0 + lr;
  const int* adjbase = adjm + ((size_t)(b * N_) + i0) * N_ + j0 + lg * 4;

  // per-lane inverse-swizzled global source offsets for my 4 stage instructions
  int soff[4];
#pragma unroll
  for (int q = 0; q < 4; ++q) {
    int y = ch * 4096 + q * 1024 + lane * 16;   // linear LDS byte this lane fills
    int row = y >> 9;
    soff[q] = y ^ ((row & 7) << 4);
  }
  const int base0 = lr * 512 + lg * 32;
  const int swz = (lr & 7) << 4;

  float mhreg[2][4];
  int4 adjreg[2];

#define GLL16(GP, LP) __builtin_amdgcn_global_load_lds((gas_void*)(GP), (las_void*)(LP), 16, 0, 0)

#define STAGE(TT, BF) do { \
    const char* gch = gedge + (size_t)(TT) * STEPB; \
    char* lb = mybuf + (BF) * CHUNK + ch * 4096; \
    GLL16(gch + soff[0], lb); \
    GLL16(gch + soff[1], lb + 1024); \
    GLL16(gch + soff[2], lb + 2048); \
    GLL16(gch + soff[3], lb + 3072); \
  } while (0)

#define REGS(TT, BF) do { \
    const float* mr = mhbase + (size_t)(TT) * C_; \
    mhreg[BF][0] = mr[0];  mhreg[BF][1] = mr[16]; \
    mhreg[BF][2] = mr[32]; mhreg[BF][3] = mr[48]; \
    adjreg[BF] = *reinterpret_cast<const int4*>(adjbase + (size_t)(TT) * N_); \
  } while (0)

#define BODY(BF, WAITA, DOSTAGE, TSTAGE) do { \
    asm volatile("s_waitcnt vmcnt(" WAITA ")\n\ts_barrier" ::: "memory"); \
    const char* rb = mybuf + (BF) * CHUNK; \
    s16x8 af[4]; \
    _Pragma("unroll") \
    for (int kb = 0; kb < 4; ++kb) { \
      int a0 = (base0 + kb * 128) ^ swz; \
      f32x4 lo = *reinterpret_cast<const f32x4*>(rb + a0); \
      f32x4 hi = *reinterpret_cast<const f32x4*>(rb + (a0 ^ 16)); \
      af[kb] = cvt8(lo, hi); \
    } \
    asm volatile("s_waitcnt lgkmcnt(0)\n\ts_barrier" ::: "memory"); \
    float mhv0 = mhreg[BF][0], mhv1 = mhreg[BF][1]; \
    float mhv2 = mhreg[BF][2], mhv3 = mhreg[BF][3]; \
    int4 av = adjreg[BF]; \
    if (DOSTAGE) { STAGE(TSTAGE, BF); REGS(TSTAGE, BF); } \
    float adjf[4] = {(float)av.x, (float)av.y, (float)av.z, (float)av.w}; \
    float mhv[4] = {mhv0, mhv1, mhv2, mhv3}; \
    _Pragma("unroll") \
    for (int nb = 0; nb < 4; ++nb) { \
      f32x4 acc; \
      _Pragma("unroll") \
      for (int r = 0; r < 4; ++r) acc[r] = cf[nb][r] + mhv[nb]; \
      _Pragma("unroll") \
      for (int kb = 0; kb < 4; ++kb) \
        acc = __builtin_amdgcn_mfma_f32_16x16x32_bf16(af[kb], bfrag[kb][nb], acc, 0, 0, 0); \
      _Pragma("unroll") \
      for (int r = 0; r < 4; ++r) mx[nb][r] = fmaxf(mx[nb][r], adjf[r] * acc[r]); \
    } \
  } while (0)

  // prologue: stage steps 0,1
  STAGE(0, 0); REGS(0, 0);
  STAGE(1, 1); REGS(1, 1);

  // steady state: steps 0..29, staging t+2 each step
  for (int o = 0; o < 15; ++o) {
    BODY(0, "9", 1, 2 * o + 2);
    BODY(1, "9", 1, 2 * o + 3);
  }
  // tail: steps 30,31 (no staging)
  BODY(0, "9", 0, 0);
  BODY(1, "0", 0, 0);

#undef BODY
#undef REGS
#undef STAGE
#undef GLL16

  float* prow = pbuf + (((size_t)s * B_ + b) * N_ + j0 + lg * 4) * C_ + n0 + lr;
#pragma unroll
  for (int nb = 0; nb < 4; ++nb)
#pragma unroll
    for (int r = 0; r < 4; ++r)
      prow[r * C_ + nb * 16] = mx[nb][r];
}

// ---------- Epilogue: S-max + node@Wo1 + hidden@Wo2 + msgs@Wo3 ----------
__global__ void k_epi(const float* __restrict__ node, const float* __restrict__ hidden,
                      const float* __restrict__ Wo1, const float* __restrict__ bo1,
                      const float* __restrict__ Wo2, const float* __restrict__ bo2,
                      const float* __restrict__ Wo3, const float* __restrict__ bo3,
                      const float* __restrict__ pbuf, float* __restrict__ out) {
  int row0 = blockIdx.x * 8;
  int col = threadIdx.x & 127;
  int half = threadIdx.x >> 7;
  __shared__ float shn[8][C_], shh[8][C_], shm[8][C_];
#pragma unroll
  for (int r = 0; r < 4; ++r) {
    int rr = half * 4 + r;
    shn[rr][col] = node[(row0 + rr) * C_ + col];
    shh[rr][col] = hidden[(row0 + rr) * C_ + col];
    float mv = -INFINITY;
#pragma unroll
    for (int s = 0; s < S_; ++s)
      mv = fmaxf(mv, pbuf[((size_t)s * (B_ * N_) + row0 + rr) * C_ + col]);
    shm[rr][col] = mv;
  }
  __syncthreads();
  float init = bo1[col] + bo2[col] + bo3[col];
  float acc[4];
#pragma unroll
  for (int r = 0; r < 4; ++r) acc[r] = init;
  for (int k = 0; k < C_; k += 8) {
    float wv1[8], wv2[8], wv3[8];
#pragma unroll
    for (int u = 0; u < 8; ++u) {
      wv1[u] = Wo1[(k + u) * C_ + col];
      wv2[u] = Wo2[(k + u) * C_ + col];
      wv3[u] = Wo3[(k + u) * C_ + col];
    }
#pragma unroll
    for (int u = 0; u < 8; ++u)
#pragma unroll
      for (int r = 0; r < 4; ++r) {
        int rr = half * 4 + r;
        acc[r] += shn[rr][k + u] * wv1[u] + shh[rr][k + u] * wv2[u] + shm[rr][k + u] * wv3[u];
      }
  }
#pragma unroll
  for (int r = 0; r < 4; ++r)
    out[(row0 + half * 4 + r) * C_ + col] = acc[r];
}

extern "C" void kernel_launch(void* const* d_in, const int* in_sizes, int n_in,
                              void* d_out, int out_size, void* d_ws, size_t ws_size,
                              hipStream_t stream) {
  const float* node   = (const float*)d_in[0];
  const float* edge   = (const float*)d_in[1];
  const float* graph  = (const float*)d_in[2];
  const int*   adjm   = (const int*)d_in[3];
  const float* hidden = (const float*)d_in[4];
  const float* Wn = (const float*)d_in[5];  const float* bn = (const float*)d_in[6];
  const float* Wh = (const float*)d_in[7];  const float* bh = (const float*)d_in[8];
  const float* We = (const float*)d_in[9];  const float* be = (const float*)d_in[10];
  const float* Wg = (const float*)d_in[11]; const float* bg = (const float*)d_in[12];
  const float* Wo1 = (const float*)d_in[13]; const float* bo1 = (const float*)d_in[14];
  const float* Wo2 = (const float*)d_in[15]; const float* bo2 = (const float*)d_in[16];
  const float* Wo3 = (const float*)d_in[17]; const float* bo3 = (const float*)d_in[18];
  float* out = (float*)d_out;

  char* ws = (char*)d_ws;
  float* ws_c  = (float*)ws;                 // 1 MB
  float* ws_mh = (float*)(ws + (1u << 20));  // 1 MB
  float* pbuf  = (float*)(ws + (2u << 20));  // 8 MB partials

  k_pro<<<512, 128, 0, stream>>>(node, hidden, graph, Wn, bn, Wh, bh, be, Wg, bg,
                                 ws_c, ws_mh);
  k_main<<<512, 256, 0, stream>>>(edge, adjm, We, ws_c, ws_mh, pbuf);
  k_epi<<<256, 256, 0, stream>>>(node, hidden, Wo1, bo1, Wo2, bo2, Wo3, bo3,
                                 pbuf, out);
}

// Round 6
// 97.227 us; speedup vs baseline: 1.4819x; 1.0047x over previous
//
#include <hip/hip_runtime.h>
#include <hip/hip_bf16.h>

// B=8, N=256, D=E=G=MID=OUT=128
#define B_ 8
#define N_ 256
#define C_ 128
#define S_ 8        // i-splits
#define CHUNK 8192  // 16 j-rows x 128 f32 = 8KB staged per pair-step (one i)
#define STEPB (N_ * C_ * 4)

typedef __attribute__((ext_vector_type(4))) float f32x4;
typedef __attribute__((ext_vector_type(8))) short s16x8;

__device__ __forceinline__ unsigned short f2bf(float f) {
  unsigned int u = __builtin_bit_cast(unsigned int, f);
  u += 0x7FFFu + ((u >> 16) & 1u);   // RNE
  return (unsigned short)(u >> 16);
}

__device__ __forceinline__ unsigned int pk2(float a, float b) {
  __hip_bfloat162 h = __float22bfloat162_rn(make_float2(a, b));
  unsigned int u;
  __builtin_memcpy(&u, &h, 4);
  return u;
}

__device__ __forceinline__ s16x8 cvt8(f32x4 lo, f32x4 hi) {
  union { unsigned int u[4]; s16x8 s; } r;
  r.u[0] = pk2(lo[0], lo[1]);
  r.u[1] = pk2(lo[2], lo[3]);
  r.u[2] = pk2(hi[0], hi[1]);
  r.u[3] = pk2(hi[2], hi[3]);
  return r.s;
}

// ---------- P: c = node@Wn+bn+be+(graph@Wg+bg) ; mh = hidden@Wh+bh ; We->ws_B ----------
// 544 blocks x 128 thr; 0..255 -> c, 256..511 -> mh, 512..543 -> ws_B frags
__global__ void k_pro(const float* __restrict__ node, const float* __restrict__ hidden,
                      const float* __restrict__ graph,
                      const float* __restrict__ Wn, const float* __restrict__ bn,
                      const float* __restrict__ Wh, const float* __restrict__ bh,
                      const float* __restrict__ be,
                      const float* __restrict__ Wg, const float* __restrict__ bg,
                      const float* __restrict__ We,
                      float* __restrict__ ws_c, float* __restrict__ ws_mh,
                      short* __restrict__ ws_B) {
  int bid = blockIdx.x, t = threadIdx.x;
  if (bid >= 512) {
    int f = bid - 512;                 // 0..31: frag f = kb*8+nb
    if (t < 64) {
      int kb = f >> 3, nb = f & 7;
      int lr = t & 15, lg = t >> 4;
      s16x8 v;
#pragma unroll
      for (int e = 0; e < 8; ++e)
        v[e] = (short)f2bf(We[(kb * 32 + lg * 8 + e) * C_ + nb * 16 + lr]);
      *reinterpret_cast<s16x8*>(ws_B + (f * 64 + t) * 8) = v;
    }
    return;
  }
  bool isc = bid < 256;
  int row0 = (isc ? bid : bid - 256) * 8;     // row = b*N + n
  const float* src = isc ? node : hidden;
  const float* W   = isc ? Wn : Wh;
  __shared__ float sh[8][C_];
#pragma unroll
  for (int r = 0; r < 8; ++r) sh[r][t] = src[(row0 + r) * C_ + t];
  __syncthreads();
  float g = 0.f;
  float acc[8];
#pragma unroll
  for (int r = 0; r < 8; ++r) acc[r] = 0.f;
  const float* gr = graph + (row0 >> 8) * C_;
  for (int k = 0; k < C_; k += 8) {
    float wv[8];
#pragma unroll
    for (int u = 0; u < 8; ++u) wv[u] = W[(k + u) * C_ + t];
    if (isc) {
      float wgv[8];
#pragma unroll
      for (int u = 0; u < 8; ++u) wgv[u] = Wg[(k + u) * C_ + t];
#pragma unroll
      for (int u = 0; u < 8; ++u) g += gr[k + u] * wgv[u];
    }
#pragma unroll
    for (int u = 0; u < 8; ++u)
#pragma unroll
      for (int r = 0; r < 8; ++r) acc[r] += sh[r][k + u] * wv[u];
  }
  float init = isc ? (bn[t] + be[t] + bg[t] + g) : bh[t];
  float* dst = isc ? ws_c : ws_mh;
#pragma unroll
  for (int r = 0; r < 8; ++r) dst[(row0 + r) * C_ + t] = acc[r] + init;
}

// ---------- Main: fused edge@We + broadcast-add + masked max ----------
// 512 WGs x 256 thr. Pair p: s = sp*2+p (32 i's); ch = col half within pair.
// Reg-staged 3-gen pipeline: plain dwordx4 global loads (deep queue) -> regs,
// counted vmcnt(18), ds_write_b128 into mod-3 LDS buffers (XOR-swizzled both sides),
// ONE lgkmcnt(0)+s_barrier per step. Never vmcnt(0) in the loop.
__global__ __launch_bounds__(256, 2) void k_main(
    const float* __restrict__ edge, const int* __restrict__ adjm,
    const short* __restrict__ ws_B,
    const float* __restrict__ ws_c, const float* __restrict__ ws_mh,
    float* __restrict__ pbuf) {
  __shared__ __align__(16) char smem[2 * 3 * CHUNK];  // 48 KB
  const int lane = threadIdx.x & 63;
  const int w = threadIdx.x >> 6;
  const int pair = w >> 1;
  const int ch = w & 1;
  const int wg = blockIdx.x;
  const int sp  = wg & 3;
  const int j16 = (wg >> 2) & 15;
  const int b   = wg >> 6;
  const int s   = sp * 2 + pair;
  const int j0 = j16 * 16;
  const int n0 = ch * 64;
  const int i0 = s * 32;
  const int lr = lane & 15;  // A-row / BCD-col
  const int lg = lane >> 4;  // k-group / row-group

  char* mybuf = smem + pair * (3 * CHUNK);

  // B fragments from precomputed ws_B (32 KB, L2-resident): 16 x dwordx4
  s16x8 bfrag[4][4];
#pragma unroll
  for (int kb = 0; kb < 4; ++kb)
#pragma unroll
    for (int nb = 0; nb < 4; ++nb)
      bfrag[kb][nb] = *reinterpret_cast<const s16x8*>(
          ws_B + ((kb * 8 + ch * 4 + nb) * 64 + lane) * 8);

  // c fragment (i-invariant part of output), loaded once
  float cf[4][4];
#pragma unroll
  for (int nb = 0; nb < 4; ++nb)
#pragma unroll
    for (int r = 0; r < 4; ++r)
      cf[nb][r] = ws_c[(b * N_ + j0 + lg * 4 + r) * C_ + n0 + nb * 16 + lr];

  f32x4 mx[4];
#pragma unroll
  for (int nb = 0; nb < 4; ++nb)
#pragma unroll
    for (int r = 0; r < 4; ++r) mx[nb][r] = -INFINITY;

  const char* gedge = (const char*)(edge + ((size_t)(b * N_ + i0) * N_ + j0) * C_);
  const float* mhbase = ws_mh + ((size_t)(b * N_) + i0) * C_ + n0 + lr;
  const int* adjbase = adjm + ((size_t)(b * N_) + i0) * N_ + j0 + lg * 4;

  // staging offsets: linear global, XOR-swizzled LDS (same XOR on read side)
  int yoff[4], ldsoff[4];
#pragma unroll
  for (int q = 0; q < 4; ++q) {
    int y = ch * 4096 + q * 1024 + lane * 16;
    int row = y >> 9;
    yoff[q] = y;
    ldsoff[q] = y ^ ((row & 7) << 4);
  }
  const int base0 = lr * 512 + lg * 32;
  const int swz = (lr & 7) << 4;

  // 3-generation register staging state
  f32x4 est[3][4];
  float mreg[3][4];
  int4  areg[3];

#define ISSUE(G, TT) do { \
    const char* gch = gedge + (size_t)(TT) * STEPB; \
    est[G][0] = *reinterpret_cast<const f32x4*>(gch + yoff[0]); \
    est[G][1] = *reinterpret_cast<const f32x4*>(gch + yoff[1]); \
    est[G][2] = *reinterpret_cast<const f32x4*>(gch + yoff[2]); \
    est[G][3] = *reinterpret_cast<const f32x4*>(gch + yoff[3]); \
    const float* mr = mhbase + (size_t)(TT) * C_; \
    mreg[G][0] = mr[0];  mreg[G][1] = mr[16]; \
    mreg[G][2] = mr[32]; mreg[G][3] = mr[48]; \
    areg[G] = *reinterpret_cast<const int4*>(adjbase + (size_t)(TT) * N_); \
  } while (0)

#define DSWRITE(G) do { \
    char* lb = mybuf + (G) * CHUNK; \
    *reinterpret_cast<f32x4*>(lb + ldsoff[0]) = est[G][0]; \
    *reinterpret_cast<f32x4*>(lb + ldsoff[1]) = est[G][1]; \
    *reinterpret_cast<f32x4*>(lb + ldsoff[2]) = est[G][2]; \
    *reinterpret_cast<f32x4*>(lb + ldsoff[3]) = est[G][3]; \
  } while (0)

  // STEP t: read buf[CUR]; consume mh/adj gen CUR; optionally issue t+3 into gen CUR;
  // wait counted vmcnt; ds_write gen NW -> buf[NW]; MFMA; lgkm(0)+barrier.
#define STEP(CUR, NW, TT, DOISSUE, DOWRITE, WAITN) do { \
    const char* rb = mybuf + (CUR) * CHUNK; \
    s16x8 af[4]; \
    _Pragma("unroll") \
    for (int kb = 0; kb < 4; ++kb) { \
      int a0 = (base0 + kb * 128) ^ swz; \
      f32x4 lo = *reinterpret_cast<const f32x4*>(rb + a0); \
      f32x4 hi = *reinterpret_cast<const f32x4*>(rb + (a0 ^ 16)); \
      af[kb] = cvt8(lo, hi); \
    } \
    float mhv[4] = {mreg[CUR][0], mreg[CUR][1], mreg[CUR][2], mreg[CUR][3]}; \
    int4 av = areg[CUR]; \
    if (DOISSUE) ISSUE(CUR, (TT) + 3); \
    if (DOWRITE) { \
      asm volatile("s_waitcnt vmcnt(" WAITN ")" ::: "memory"); \
      DSWRITE(NW); \
    } \
    float adjf[4] = {(float)av.x, (float)av.y, (float)av.z, (float)av.w}; \
    _Pragma("unroll") \
    for (int nb = 0; nb < 4; ++nb) { \
      f32x4 acc; \
      _Pragma("unroll") \
      for (int r = 0; r < 4; ++r) acc[r] = cf[nb][r] + mhv[nb]; \
      _Pragma("unroll") \
      for (int kb = 0; kb < 4; ++kb) \
        acc = __builtin_amdgcn_mfma_f32_16x16x32_bf16(af[kb], bfrag[kb][nb], acc, 0, 0, 0); \
      _Pragma("unroll") \
      for (int r = 0; r < 4; ++r) mx[nb][r] = fmaxf(mx[nb][r], adjf[r] * acc[r]); \
    } \
    asm volatile("s_waitcnt lgkmcnt(0)\n\ts_barrier" ::: "memory"); \
  } while (0)

  // prologue: 3 generations in flight; write buf0; barrier
  ISSUE(0, 0);
  ISSUE(1, 1);
  ISSUE(2, 2);
  asm volatile("s_waitcnt vmcnt(18)" ::: "memory");
  DSWRITE(0);
  asm volatile("s_waitcnt lgkmcnt(0)\n\ts_barrier" ::: "memory");

  // steady: t = 0..28 (issue t+3 <= 31), tails 29..31
  for (int o = 0; o < 9; ++o) {
    STEP(0, 1, 3 * o,     1, 1, "18");
    STEP(1, 2, 3 * o + 1, 1, 1, "18");
    STEP(2, 0, 3 * o + 2, 1, 1, "18");
  }
  STEP(0, 1, 27, 1, 1, "18");
  STEP(1, 2, 28, 1, 1, "18");
  STEP(2, 0, 29, 0, 1, "9");
  STEP(0, 1, 30, 0, 1, "0");
  STEP(1, 2, 31, 0, 0, "0");

#undef STEP
#undef DSWRITE
#undef ISSUE

  float* prow = pbuf + (((size_t)s * B_ + b) * N_ + j0 + lg * 4) * C_ + n0 + lr;
#pragma unroll
  for (int nb = 0; nb < 4; ++nb)
#pragma unroll
    for (int r = 0; r < 4; ++r)
      prow[r * C_ + nb * 16] = mx[nb][r];
}

// ---------- Epilogue: S-max + node@Wo1 + hidden@Wo2 + msgs@Wo3 ----------
__global__ void k_epi(const float* __restrict__ node, const float* __restrict__ hidden,
                      const float* __restrict__ Wo1, const float* __restrict__ bo1,
                      const float* __restrict__ Wo2, const float* __restrict__ bo2,
                      const float* __restrict__ Wo3, const float* __restrict__ bo3,
                      const float* __restrict__ pbuf, float* __restrict__ out) {
  int row0 = blockIdx.x * 8;
  int col = threadIdx.x & 127;
  int half = threadIdx.x >> 7;
  __shared__ float shn[8][C_], shh[8][C_], shm[8][C_];
#pragma unroll
  for (int r = 0; r < 4; ++r) {
    int rr = half * 4 + r;
    shn[rr][col] = node[(row0 + rr) * C_ + col];
    shh[rr][col] = hidden[(row0 + rr) * C_ + col];
    float mv = -INFINITY;
#pragma unroll
    for (int s = 0; s < S_; ++s)
      mv = fmaxf(mv, pbuf[((size_t)s * (B_ * N_) + row0 + rr) * C_ + col]);
    shm[rr][col] = mv;
  }
  __syncthreads();
  float init = bo1[col] + bo2[col] + bo3[col];
  float acc[4];
#pragma unroll
  for (int r = 0; r < 4; ++r) acc[r] = init;
  for (int k = 0; k < C_; k += 8) {
    float wv1[8], wv2[8], wv3[8];
#pragma unroll
    for (int u = 0; u < 8; ++u) {
      wv1[u] = Wo1[(k + u) * C_ + col];
      wv2[u] = Wo2[(k + u) * C_ + col];
      wv3[u] = Wo3[(k + u) * C_ + col];
    }
#pragma unroll
    for (int u = 0; u < 8; ++u)
#pragma unroll
      for (int r = 0; r < 4; ++r) {
        int rr = half * 4 + r;
        acc[r] += shn[rr][k + u] * wv1[u] + shh[rr][k + u] * wv2[u] + shm[rr][k + u] * wv3[u];
      }
  }
#pragma unroll
  for (int r = 0; r < 4; ++r)
    out[(row0 + half * 4 + r) * C_ + col] = acc[r];
}

extern "C" void kernel_launch(void* const* d_in, const int* in_sizes, int n_in,
                              void* d_out, int out_size, void* d_ws, size_t ws_size,
                              hipStream_t stream) {
  const float* node   = (const float*)d_in[0];
  const float* edge   = (const float*)d_in[1];
  const float* graph  = (const float*)d_in[2];
  const int*   adjm   = (const int*)d_in[3];
  const float* hidden = (const float*)d_in[4];
  const float* Wn = (const float*)d_in[5];  const float* bn = (const float*)d_in[6];
  const float* Wh = (const float*)d_in[7];  const float* bh = (const float*)d_in[8];
  const float* We = (const float*)d_in[9];  const float* be = (const float*)d_in[10];
  const float* Wg = (const float*)d_in[11]; const float* bg = (const float*)d_in[12];
  const float* Wo1 = (const float*)d_in[13]; const float* bo1 = (const float*)d_in[14];
  const float* Wo2 = (const float*)d_in[15]; const float* bo2 = (const float*)d_in[16];
  const float* Wo3 = (const float*)d_in[17]; const float* bo3 = (const float*)d_in[18];
  float* out = (float*)d_out;

  char* ws = (char*)d_ws;
  float* ws_c  = (float*)ws;                 // 1 MB
  float* ws_mh = (float*)(ws + (1u << 20));  // 1 MB
  short* ws_B  = (short*)(ws + (2u << 20));  // 32 KB
  float* pbuf  = (float*)(ws + (4u << 20));  // 8 MB partials

  k_pro<<<544, 128, 0, stream>>>(node, hidden, graph, Wn, bn, Wh, bh, be, Wg, bg, We,
                                 ws_c, ws_mh, ws_B);
  k_main<<<512, 256, 0, stream>>>(edge, adjm, ws_B, ws_c, ws_mh, pbuf);
  k_epi<<<256, 256, 0, stream>>>(node, hidden, Wo1, bo1, Wo2, bo2, Wo3, bo3,
                                 pbuf, out);
}

// Round 7
// 87.919 us; speedup vs baseline: 1.6388x; 1.1059x over previous
//
#include <hip/hip_runtime.h>
#include <hip/hip_bf16.h>

// B=8, N=256, D=E=G=MID=OUT=128
#define B_ 8
#define N_ 256
#define C_ 128
#define S_ 8
#define STEPB (N_ * C_ * 4)   // 128KB between consecutive i

typedef __attribute__((ext_vector_type(4))) float f32x4;
typedef __attribute__((ext_vector_type(2))) float f32x2;
typedef __attribute__((ext_vector_type(8))) short s16x8;

typedef __attribute__((address_space(1))) const void gas_void;
typedef __attribute__((address_space(3))) void las_void;

__device__ __forceinline__ unsigned short f2bf(float f) {
  unsigned int u = __builtin_bit_cast(unsigned int, f);
  u += 0x7FFFu + ((u >> 16) & 1u);   // RNE
  return (unsigned short)(u >> 16);
}

__device__ __forceinline__ unsigned int pk2(float a, float b) {
  __hip_bfloat162 h = __float22bfloat162_rn(make_float2(a, b));
  unsigned int u;
  __builtin_memcpy(&u, &h, 4);
  return u;
}

__device__ __forceinline__ s16x8 cvt8(f32x4 lo, f32x4 hi) {
  union { unsigned int u[4]; s16x8 s; } r;
  r.u[0] = pk2(lo[0], lo[1]);
  r.u[1] = pk2(lo[2], lo[3]);
  r.u[2] = pk2(hi[0], hi[1]);
  r.u[3] = pk2(hi[2], hi[3]);
  return r.s;
}

// ---------- P: c = node@Wn+bn+be+(graph@Wg+bg) ; mh2 = frag-packed hidden@Wh+bh ; We->ws_B ----------
// 544 blocks x 128 thr; 0..255 -> c, 256..511 -> mh2, 512..543 -> ws_B frags
__global__ void k_pro(const float* __restrict__ node, const float* __restrict__ hidden,
                      const float* __restrict__ graph,
                      const float* __restrict__ Wn, const float* __restrict__ bn,
                      const float* __restrict__ Wh, const float* __restrict__ bh,
                      const float* __restrict__ be,
                      const float* __restrict__ Wg, const float* __restrict__ bg,
                      const float* __restrict__ We,
                      float* __restrict__ ws_c, float* __restrict__ ws_mh2,
                      short* __restrict__ ws_B) {
  int bid = blockIdx.x, t = threadIdx.x;
  if (bid >= 512) {
    int f = bid - 512;                 // 0..31: frag f = kb*8+nbg
    if (t < 64) {
      int kb = f >> 3, nbg = f & 7;
      int lr = t & 15, lg = t >> 4;
      s16x8 v;
#pragma unroll
      for (int e = 0; e < 8; ++e)
        v[e] = (short)f2bf(We[(kb * 32 + lg * 8 + e) * C_ + nbg * 16 + lr]);
      *reinterpret_cast<s16x8*>(ws_B + (f * 64 + t) * 8) = v;
    }
    return;
  }
  bool isc = bid < 256;
  int row0 = (isc ? bid : bid - 256) * 8;     // row = b*N + n
  const float* src = isc ? node : hidden;
  const float* W   = isc ? Wn : Wh;
  __shared__ float sh[8][C_];
#pragma unroll
  for (int r = 0; r < 8; ++r) sh[r][t] = src[(row0 + r) * C_ + t];
  __syncthreads();
  float g = 0.f;
  float acc[8];
#pragma unroll
  for (int r = 0; r < 8; ++r) acc[r] = 0.f;
  const float* gr = graph + (row0 >> 8) * C_;
  for (int k = 0; k < C_; k += 8) {
    float wv[8];
#pragma unroll
    for (int u = 0; u < 8; ++u) wv[u] = W[(k + u) * C_ + t];
    if (isc) {
      float wgv[8];
#pragma unroll
      for (int u = 0; u < 8; ++u) wgv[u] = Wg[(k + u) * C_ + t];
#pragma unroll
      for (int u = 0; u < 8; ++u) g += gr[k + u] * wgv[u];
    }
#pragma unroll
    for (int u = 0; u < 8; ++u)
#pragma unroll
      for (int r = 0; r < 8; ++r) acc[r] += sh[r][k + u] * wv[u];
  }
  if (isc) {
    float init = bn[t] + be[t] + bg[t] + g;
#pragma unroll
    for (int r = 0; r < 8; ++r) ws_c[(row0 + r) * C_ + t] = acc[r] + init;
  } else {
    float init = bh[t];
    // fragment-packed layout: col c -> p = (c>>5)*32 + (c&15)*2 + ((c>>4)&1)
    int p = (t >> 5) * 32 + (t & 15) * 2 + ((t >> 4) & 1);
#pragma unroll
    for (int r = 0; r < 8; ++r) ws_mh2[(row0 + r) * C_ + p] = acc[r] + init;
  }
}

// ---------- Main: fused edge@We + broadcast-add + masked max ----------
// 1024 blocks (b, j16, s) x 256 thr (4 waves). Wave w owns 32 cols (n0 = w*32).
// 4-slot LDS ring (8KB each), GLL staging of gen t+3, ONE vmcnt(8)+s_barrier per step.
// XOR-swizzle: linear LDS dest + inverse-swizzled global src + swizzled ds_read.
__global__ __launch_bounds__(256, 3) void k_main(
    const float* __restrict__ edge, const int* __restrict__ adjm,
    const short* __restrict__ ws_B,
    const float* __restrict__ ws_c, const float* __restrict__ ws_mh2,
    float* __restrict__ pbuf) {
  __shared__ __align__(16) char smem[4 * 8192];  // 32 KB
  const int lane = threadIdx.x & 63;
  const int w = threadIdx.x >> 6;
  const int wg = blockIdx.x;
  const int s   = wg & 7;
  const int j16 = (wg >> 3) & 15;
  const int b   = wg >> 7;
  const int j0 = j16 * 16;
  const int n0 = w * 32;
  const int i0 = s * 32;
  const int lr = lane & 15;  // A-row / BCD-col
  const int lg = lane >> 4;  // k-group / row-group

  // B fragments (32 cols) from precomputed ws_B
  s16x8 bfrag[4][2];
#pragma unroll
  for (int kb = 0; kb < 4; ++kb)
#pragma unroll
    for (int nb = 0; nb < 2; ++nb)
      bfrag[kb][nb] = *reinterpret_cast<const s16x8*>(
          ws_B + ((kb * 8 + w * 2 + nb) * 64 + lane) * 8);

  // c fragment (j-invariant part of output), loaded once
  float cf[2][4];
#pragma unroll
  for (int nb = 0; nb < 2; ++nb)
#pragma unroll
    for (int r = 0; r < 4; ++r)
      cf[nb][r] = ws_c[(b * N_ + j0 + lg * 4 + r) * C_ + n0 + nb * 16 + lr];

  f32x4 mx[2];
#pragma unroll
  for (int nb = 0; nb < 2; ++nb)
#pragma unroll
    for (int r = 0; r < 4; ++r) mx[nb][r] = -INFINITY;

  const char* gedge = (const char*)(edge + ((size_t)(b * N_ + i0) * N_ + j0) * C_);
  const float* mh2 = ws_mh2 + ((size_t)(b * N_) + i0) * C_ + n0 + lr * 2;
  const int* adjb = adjm + ((size_t)(b * N_) + i0) * N_ + j0 + lg * 4;

  // staging: wave w stages bytes [w*2048, w*2048+2048) of each 8KB chunk
  int soff[2];
#pragma unroll
  for (int q = 0; q < 2; ++q) {
    int y = w * 2048 + q * 1024 + lane * 16;  // linear LDS byte
    int row = y >> 9;
    soff[q] = y ^ ((row & 7) << 4);           // inverse-swizzled global src
  }
  const int base0 = lr * 512 + lg * 32;
  const int swz = (lr & 7) << 4;

  f32x2 mreg[4];
  int4  areg[4];

#define GLL16(GP, LP) __builtin_amdgcn_global_load_lds((gas_void*)(GP), (las_void*)(LP), 16, 0, 0)

#define ISSUE(SL, TT) do { \
    const char* gch = gedge + (size_t)(TT) * STEPB; \
    char* lb = smem + (SL) * 8192 + w * 2048; \
    GLL16(gch + soff[0], lb); \
    GLL16(gch + soff[1], lb + 1024); \
    mreg[SL] = *reinterpret_cast<const f32x2*>(mh2 + (size_t)(TT) * C_); \
    areg[SL] = *reinterpret_cast<const int4*>(adjb + (size_t)(TT) * N_); \
  } while (0)

#define STEP(SL, ISL, WAITN, DOISSUE, TI) do { \
    asm volatile("s_waitcnt vmcnt(" WAITN ")\n\ts_barrier" ::: "memory"); \
    const char* rb = smem + (SL) * 8192; \
    f32x4 lo[4], hi[4]; \
    _Pragma("unroll") \
    for (int kb = 0; kb < 4; ++kb) { \
      int a0 = (base0 + kb * 128) ^ swz; \
      lo[kb] = *reinterpret_cast<const f32x4*>(rb + a0); \
      hi[kb] = *reinterpret_cast<const f32x4*>(rb + (a0 ^ 16)); \
    } \
    if (DOISSUE) ISSUE(ISL, TI); \
    s16x8 af[4]; \
    _Pragma("unroll") \
    for (int kb = 0; kb < 4; ++kb) af[kb] = cvt8(lo[kb], hi[kb]); \
    f32x2 mh = mreg[SL]; \
    int4 av = areg[SL]; \
    float adjf[4] = {(float)av.x, (float)av.y, (float)av.z, (float)av.w}; \
    _Pragma("unroll") \
    for (int nb = 0; nb < 2; ++nb) { \
      f32x4 acc; \
      _Pragma("unroll") \
      for (int r = 0; r < 4; ++r) acc[r] = cf[nb][r] + mh[nb]; \
      _Pragma("unroll") \
      for (int kb = 0; kb < 4; ++kb) \
        acc = __builtin_amdgcn_mfma_f32_16x16x32_bf16(af[kb], bfrag[kb][nb], acc, 0, 0, 0); \
      _Pragma("unroll") \
      for (int r = 0; r < 4; ++r) mx[nb][r] = fmaxf(mx[nb][r], adjf[r] * acc[r]); \
    } \
  } while (0)

  // prologue: gens 0,1,2 in flight (4 VMEM each)
  ISSUE(0, 0);
  ISSUE(1, 1);
  ISSUE(2, 2);

  // steady: t=0..27 (issue gens 3..30), then t=28 (issue 31), tails 29..31
  for (int o = 0; o < 7; ++o) {
    STEP(0, 3, "8", 1, 4 * o + 3);
    STEP(1, 0, "8", 1, 4 * o + 4);
    STEP(2, 1, "8", 1, 4 * o + 5);
    STEP(3, 2, "8", 1, 4 * o + 6);
  }
  STEP(0, 3, "8", 1, 31);
  STEP(1, 0, "8", 0, 0);
  STEP(2, 1, "4", 0, 0);
  STEP(3, 2, "0", 0, 0);

#undef STEP
#undef ISSUE
#undef GLL16

  float* prow = pbuf + (((size_t)s * B_ + b) * N_ + j0 + lg * 4) * C_ + n0 + lr;
#pragma unroll
  for (int nb = 0; nb < 2; ++nb)
#pragma unroll
    for (int r = 0; r < 4; ++r)
      prow[r * C_ + nb * 16] = mx[nb][r];
}

// ---------- Epilogue: S-max + node@Wo1 + hidden@Wo2 + msgs@Wo3 ----------
__global__ void k_epi(const float* __restrict__ node, const float* __restrict__ hidden,
                      const float* __restrict__ Wo1, const float* __restrict__ bo1,
                      const float* __restrict__ Wo2, const float* __restrict__ bo2,
                      const float* __restrict__ Wo3, const float* __restrict__ bo3,
                      const float* __restrict__ pbuf, float* __restrict__ out) {
  int row0 = blockIdx.x * 8;
  int col = threadIdx.x & 127;
  int half = threadIdx.x >> 7;
  __shared__ float shn[8][C_], shh[8][C_], shm[8][C_];
#pragma unroll
  for (int r = 0; r < 4; ++r) {
    int rr = half * 4 + r;
    shn[rr][col] = node[(row0 + rr) * C_ + col];
    shh[rr][col] = hidden[(row0 + rr) * C_ + col];
    float mv = -INFINITY;
#pragma unroll
    for (int s = 0; s < S_; ++s)
      mv = fmaxf(mv, pbuf[((size_t)s * (B_ * N_) + row0 + rr) * C_ + col]);
    shm[rr][col] = mv;
  }
  __syncthreads();
  float init = bo1[col] + bo2[col] + bo3[col];
  float acc[4];
#pragma unroll
  for (int r = 0; r < 4; ++r) acc[r] = init;
  for (int k = 0; k < C_; k += 8) {
    float wv1[8], wv2[8], wv3[8];
#pragma unroll
    for (int u = 0; u < 8; ++u) {
      wv1[u] = Wo1[(k + u) * C_ + col];
      wv2[u] = Wo2[(k + u) * C_ + col];
      wv3[u] = Wo3[(k + u) * C_ + col];
    }
#pragma unroll
    for (int u = 0; u < 8; ++u)
#pragma unroll
      for (int r = 0; r < 4; ++r) {
        int rr = half * 4 + r;
        acc[r] += shn[rr][k + u] * wv1[u] + shh[rr][k + u] * wv2[u] + shm[rr][k + u] * wv3[u];
      }
  }
#pragma unroll
  for (int r = 0; r < 4; ++r)
    out[(row0 + half * 4 + r) * C_ + col] = acc[r];
}

extern "C" void kernel_launch(void* const* d_in, const int* in_sizes, int n_in,
                              void* d_out, int out_size, void* d_ws, size_t ws_size,
                              hipStream_t stream) {
  const float* node   = (const float*)d_in[0];
  const float* edge   = (const float*)d_in[1];
  const float* graph  = (const float*)d_in[2];
  const int*   adjm   = (const int*)d_in[3];
  const float* hidden = (const float*)d_in[4];
  const float* Wn = (const float*)d_in[5];  const float* bn = (const float*)d_in[6];
  const float* Wh = (const float*)d_in[7];  const float* bh = (const float*)d_in[8];
  const float* We = (const float*)d_in[9];  const float* be = (const float*)d_in[10];
  const float* Wg = (const float*)d_in[11]; const float* bg = (const float*)d_in[12];
  const float* Wo1 = (const float*)d_in[13]; const float* bo1 = (const float*)d_in[14];
  const float* Wo2 = (const float*)d_in[15]; const float* bo2 = (const float*)d_in[16];
  const float* Wo3 = (const float*)d_in[17]; const float* bo3 = (const float*)d_in[18];
  float* out = (float*)d_out;

  char* ws = (char*)d_ws;
  float* ws_c   = (float*)ws;                 // 1 MB
  float* ws_mh2 = (float*)(ws + (1u << 20));  // 1 MB (fragment-packed)
  short* ws_B   = (short*)(ws + (2u << 20));  // 32 KB
  float* pbuf   = (float*)(ws + (4u << 20));  // 8 MB partials

  k_pro<<<544, 128, 0, stream>>>(node, hidden, graph, Wn, bn, Wh, bh, be, Wg, bg, We,
                                 ws_c, ws_mh2, ws_B);
  k_main<<<1024, 256, 0, stream>>>(edge, adjm, ws_B, ws_c, ws_mh2, pbuf);
  k_epi<<<256, 256, 0, stream>>>(node, hidden, Wo1, bo1, Wo2, bo2, Wo3, bo3,
                                 pbuf, out);
}

// Round 8
// 87.810 us; speedup vs baseline: 1.6408x; 1.0012x over previous
//
#include <hip/hip_runtime.h>
#include <hip/hip_bf16.h>

// B=8, N=256, D=E=G=MID=OUT=128
#define B_ 8
#define N_ 256
#define C_ 128
#define S_ 8
#define STEPB (N_ * C_ * 4)   // 128KB between consecutive i

typedef __attribute__((ext_vector_type(4))) float f32x4;
typedef __attribute__((ext_vector_type(2))) float f32x2;
typedef __attribute__((ext_vector_type(8))) short s16x8;

typedef __attribute__((address_space(1))) const void gas_void;
typedef __attribute__((address_space(3))) void las_void;

__device__ __forceinline__ unsigned short f2bf(float f) {
  unsigned int u = __builtin_bit_cast(unsigned int, f);
  u += 0x7FFFu + ((u >> 16) & 1u);   // RNE
  return (unsigned short)(u >> 16);
}

__device__ __forceinline__ unsigned int pk2(float a, float b) {
  __hip_bfloat162 h = __float22bfloat162_rn(make_float2(a, b));
  unsigned int u;
  __builtin_memcpy(&u, &h, 4);
  return u;
}

__device__ __forceinline__ s16x8 cvt8(f32x4 lo, f32x4 hi) {
  union { unsigned int u[4]; s16x8 s; } r;
  r.u[0] = pk2(lo[0], lo[1]);
  r.u[1] = pk2(lo[2], lo[3]);
  r.u[2] = pk2(hi[0], hi[1]);
  r.u[3] = pk2(hi[2], hi[3]);
  return r.s;
}

// ---------- P: c = node@Wn+bn+be+(graph@Wg+bg) ; mh2 = frag-packed hidden@Wh+bh ; We->ws_B ----------
__global__ void k_pro(const float* __restrict__ node, const float* __restrict__ hidden,
                      const float* __restrict__ graph,
                      const float* __restrict__ Wn, const float* __restrict__ bn,
                      const float* __restrict__ Wh, const float* __restrict__ bh,
                      const float* __restrict__ be,
                      const float* __restrict__ Wg, const float* __restrict__ bg,
                      const float* __restrict__ We,
                      float* __restrict__ ws_c, float* __restrict__ ws_mh2,
                      short* __restrict__ ws_B) {
  int bid = blockIdx.x, t = threadIdx.x;
  if (bid >= 512) {
    int f = bid - 512;                 // 0..31: frag f = kb*8+nbg
    if (t < 64) {
      int kb = f >> 3, nbg = f & 7;
      int lr = t & 15, lg = t >> 4;
      s16x8 v;
#pragma unroll
      for (int e = 0; e < 8; ++e)
        v[e] = (short)f2bf(We[(kb * 32 + lg * 8 + e) * C_ + nbg * 16 + lr]);
      *reinterpret_cast<s16x8*>(ws_B + (f * 64 + t) * 8) = v;
    }
    return;
  }
  bool isc = bid < 256;
  int row0 = (isc ? bid : bid - 256) * 8;     // row = b*N + n
  const float* src = isc ? node : hidden;
  const float* W   = isc ? Wn : Wh;
  __shared__ float sh[8][C_];
#pragma unroll
  for (int r = 0; r < 8; ++r) sh[r][t] = src[(row0 + r) * C_ + t];
  __syncthreads();
  float g = 0.f;
  float acc[8];
#pragma unroll
  for (int r = 0; r < 8; ++r) acc[r] = 0.f;
  const float* gr = graph + (row0 >> 8) * C_;
  for (int k = 0; k < C_; k += 8) {
    float wv[8];
#pragma unroll
    for (int u = 0; u < 8; ++u) wv[u] = W[(k + u) * C_ + t];
    if (isc) {
      float wgv[8];
#pragma unroll
      for (int u = 0; u < 8; ++u) wgv[u] = Wg[(k + u) * C_ + t];
#pragma unroll
      for (int u = 0; u < 8; ++u) g += gr[k + u] * wgv[u];
    }
#pragma unroll
    for (int u = 0; u < 8; ++u)
#pragma unroll
      for (int r = 0; r < 8; ++r) acc[r] += sh[r][k + u] * wv[u];
  }
  if (isc) {
    float init = bn[t] + be[t] + bg[t] + g;
#pragma unroll
    for (int r = 0; r < 8; ++r) ws_c[(row0 + r) * C_ + t] = acc[r] + init;
  } else {
    float init = bh[t];
    // fragment-packed layout: col c -> p = (c>>5)*32 + (c&15)*2 + ((c>>4)&1)
    int p = (t >> 5) * 32 + (t & 15) * 2 + ((t >> 4) & 1);
#pragma unroll
    for (int r = 0; r < 8; ++r) ws_mh2[(row0 + r) * C_ + p] = acc[r] + init;
  }
}

// ---------- Main: fused edge@We + broadcast-add + masked max ----------
// 1024 blocks (b, j16, s) x 256 thr (4 waves). Wave w owns 32 cols (n0 = w*32).
// 3-slot LDS ring (8KB each, 24KB total), GLL staging of gen t+2 issued right
// after the top-of-step barrier, ONE vmcnt(4)+s_barrier per step.
// Target 4 blocks/CU (16 waves/CU): launch_bounds(256,4) caps VGPR at 128.
__global__ __launch_bounds__(256, 4) void k_main(
    const float* __restrict__ edge, const int* __restrict__ adjm,
    const short* __restrict__ ws_B,
    const float* __restrict__ ws_c, const float* __restrict__ ws_mh2,
    float* __restrict__ pbuf) {
  __shared__ __align__(16) char smem[3 * 8192];  // 24 KB
  const int lane = threadIdx.x & 63;
  const int w = threadIdx.x >> 6;
  const int wg = blockIdx.x;
  const int s   = wg & 7;
  const int j16 = (wg >> 3) & 15;
  const int b   = wg >> 7;
  const int j0 = j16 * 16;
  const int n0 = w * 32;
  const int i0 = s * 32;
  const int lr = lane & 15;  // A-row / BCD-col
  const int lg = lane >> 4;  // k-group / row-group

  // B fragments (32 cols) from precomputed ws_B
  s16x8 bfrag[4][2];
#pragma unroll
  for (int kb = 0; kb < 4; ++kb)
#pragma unroll
    for (int nb = 0; nb < 2; ++nb)
      bfrag[kb][nb] = *reinterpret_cast<const s16x8*>(
          ws_B + ((kb * 8 + w * 2 + nb) * 64 + lane) * 8);

  // c fragment (i-invariant part of output), loaded once
  float cf[2][4];
#pragma unroll
  for (int nb = 0; nb < 2; ++nb)
#pragma unroll
    for (int r = 0; r < 4; ++r)
      cf[nb][r] = ws_c[(b * N_ + j0 + lg * 4 + r) * C_ + n0 + nb * 16 + lr];

  f32x4 mx[2];
#pragma unroll
  for (int nb = 0; nb < 2; ++nb)
#pragma unroll
    for (int r = 0; r < 4; ++r) mx[nb][r] = -INFINITY;

  const char* gedge = (const char*)(edge + ((size_t)(b * N_ + i0) * N_ + j0) * C_);
  const float* mh2 = ws_mh2 + ((size_t)(b * N_) + i0) * C_ + n0 + lr * 2;
  const int* adjb = adjm + ((size_t)(b * N_) + i0) * N_ + j0 + lg * 4;

  // staging: wave w stages bytes [w*2048, w*2048+2048) of each 8KB chunk
  int soff[2];
#pragma unroll
  for (int q = 0; q < 2; ++q) {
    int y = w * 2048 + q * 1024 + lane * 16;  // linear LDS byte
    int row = y >> 9;
    soff[q] = y ^ ((row & 7) << 4);           // inverse-swizzled global src
  }
  const int base0 = lr * 512 + lg * 32;
  const int swz = (lr & 7) << 4;

  f32x2 mreg[3];
  int4  areg[3];

#define GLL16(GP, LP) __builtin_amdgcn_global_load_lds((gas_void*)(GP), (las_void*)(LP), 16, 0, 0)

#define ISSUE(SL, TT) do { \
    const char* gch = gedge + (size_t)(TT) * STEPB; \
    char* lb = smem + (SL) * 8192 + w * 2048; \
    GLL16(gch + soff[0], lb); \
    GLL16(gch + soff[1], lb + 1024); \
    mreg[SL] = *reinterpret_cast<const f32x2*>(mh2 + (size_t)(TT) * C_); \
    areg[SL] = *reinterpret_cast<const int4*>(adjb + (size_t)(TT) * N_); \
  } while (0)

#define STEP(SL, ISL, WAITN, DOISSUE, TI) do { \
    asm volatile("s_waitcnt vmcnt(" WAITN ")\n\ts_barrier" ::: "memory"); \
    if (DOISSUE) ISSUE(ISL, TI); \
    const char* rb = smem + (SL) * 8192; \
    s16x8 af[4]; \
    _Pragma("unroll") \
    for (int kb = 0; kb < 4; ++kb) { \
      int a0 = (base0 + kb * 128) ^ swz; \
      f32x4 lo = *reinterpret_cast<const f32x4*>(rb + a0); \
      f32x4 hi = *reinterpret_cast<const f32x4*>(rb + (a0 ^ 16)); \
      af[kb] = cvt8(lo, hi); \
    } \
    f32x2 mh = mreg[SL]; \
    int4 av = areg[SL]; \
    float adjf[4] = {(float)av.x, (float)av.y, (float)av.z, (float)av.w}; \
    _Pragma("unroll") \
    for (int nb = 0; nb < 2; ++nb) { \
      f32x4 acc; \
      _Pragma("unroll") \
      for (int r = 0; r < 4; ++r) acc[r] = cf[nb][r] + mh[nb]; \
      _Pragma("unroll") \
      for (int kb = 0; kb < 4; ++kb) \
        acc = __builtin_amdgcn_mfma_f32_16x16x32_bf16(af[kb], bfrag[kb][nb], acc, 0, 0, 0); \
      _Pragma("unroll") \
      for (int r = 0; r < 4; ++r) mx[nb][r] = fmaxf(mx[nb][r], adjf[r] * acc[r]); \
    } \
  } while (0)

  // prologue: gens 0,1 in flight (4 VMEM each)
  ISSUE(0, 0);
  ISSUE(1, 1);

  // steady: t = 0..29 (issue gens 2..31); tails t = 30, 31
  for (int o = 0; o < 10; ++o) {
    STEP(0, 2, "4", 1, 3 * o + 2);
    STEP(1, 0, "4", 1, 3 * o + 3);
    STEP(2, 1, "4", 1, 3 * o + 4);
  }
  STEP(0, 2, "4", 0, 0);   // t=30 (slot 0); gen31 still outstanding
  STEP(1, 0, "0", 0, 0);   // t=31 (slot 1)

#undef STEP
#undef ISSUE
#undef GLL16

  float* prow = pbuf + (((size_t)s * B_ + b) * N_ + j0 + lg * 4) * C_ + n0 + lr;
#pragma unroll
  for (int nb = 0; nb < 2; ++nb)
#pragma unroll
    for (int r = 0; r < 4; ++r)
      prow[r * C_ + nb * 16] = mx[nb][r];
}

// ---------- Epilogue: S-max + node@Wo1 + hidden@Wo2 + msgs@Wo3 ----------
// 512 blocks x 256 thr; block = 4 rows, thread (col = t&127, half = t>>7) does 2 rows
__global__ void k_epi(const float* __restrict__ node, const float* __restrict__ hidden,
                      const float* __restrict__ Wo1, const float* __restrict__ bo1,
                      const float* __restrict__ Wo2, const float* __restrict__ bo2,
                      const float* __restrict__ Wo3, const float* __restrict__ bo3,
                      const float* __restrict__ pbuf, float* __restrict__ out) {
  int row0 = blockIdx.x * 4;
  int col = threadIdx.x & 127;
  int half = threadIdx.x >> 7;
  __shared__ float shn[4][C_], shh[4][C_], shm[4][C_];
#pragma unroll
  for (int r = 0; r < 2; ++r) {
    int rr = half * 2 + r;
    shn[rr][col] = node[(row0 + rr) * C_ + col];
    shh[rr][col] = hidden[(row0 + rr) * C_ + col];
    float mv = -INFINITY;
#pragma unroll
    for (int s = 0; s < S_; ++s)
      mv = fmaxf(mv, pbuf[((size_t)s * (B_ * N_) + row0 + rr) * C_ + col]);
    shm[rr][col] = mv;
  }
  __syncthreads();
  float init = bo1[col] + bo2[col] + bo3[col];
  float acc[2];
  acc[0] = init; acc[1] = init;
  for (int k = 0; k < C_; k += 8) {
    float wv1[8], wv2[8], wv3[8];
#pragma unroll
    for (int u = 0; u < 8; ++u) {
      wv1[u] = Wo1[(k + u) * C_ + col];
      wv2[u] = Wo2[(k + u) * C_ + col];
      wv3[u] = Wo3[(k + u) * C_ + col];
    }
#pragma unroll
    for (int u = 0; u < 8; ++u)
#pragma unroll
      for (int r = 0; r < 2; ++r) {
        int rr = half * 2 + r;
        acc[r] += shn[rr][k + u] * wv1[u] + shh[rr][k + u] * wv2[u] + shm[rr][k + u] * wv3[u];
      }
  }
#pragma unroll
  for (int r = 0; r < 2; ++r)
    out[(row0 + half * 2 + r) * C_ + col] = acc[r];
}

extern "C" void kernel_launch(void* const* d_in, const int* in_sizes, int n_in,
                              void* d_out, int out_size, void* d_ws, size_t ws_size,
                              hipStream_t stream) {
  const float* node   = (const float*)d_in[0];
  const float* edge   = (const float*)d_in[1];
  const float* graph  = (const float*)d_in[2];
  const int*   adjm   = (const int*)d_in[3];
  const float* hidden = (const float*)d_in[4];
  const float* Wn = (const float*)d_in[5];  const float* bn = (const float*)d_in[6];
  const float* Wh = (const float*)d_in[7];  const float* bh = (const float*)d_in[8];
  const float* We = (const float*)d_in[9];  const float* be = (const float*)d_in[10];
  const float* Wg = (const float*)d_in[11]; const float* bg = (const float*)d_in[12];
  const float* Wo1 = (const float*)d_in[13]; const float* bo1 = (const float*)d_in[14];
  const float* Wo2 = (const float*)d_in[15]; const float* bo2 = (const float*)d_in[16];
  const float* Wo3 = (const float*)d_in[17]; const float* bo3 = (const float*)d_in[18];
  float* out = (float*)d_out;

  char* ws = (char*)d_ws;
  float* ws_c   = (float*)ws;                 // 1 MB
  float* ws_mh2 = (float*)(ws + (1u << 20));  // 1 MB (fragment-packed)
  short* ws_B   = (short*)(ws + (2u << 20));  // 32 KB
  float* pbuf   = (float*)(ws + (4u << 20));  // 8 MB partials

  k_pro<<<544, 128, 0, stream>>>(node, hidden, graph, Wn, bn, Wh, bh, be, Wg, bg, We,
                                 ws_c, ws_mh2, ws_B);
  k_main<<<1024, 256, 0, stream>>>(edge, adjm, ws_B, ws_c, ws_mh2, pbuf);
  k_epi<<<512, 256, 0, stream>>>(node, hidden, Wo1, bo1, Wo2, bo2, Wo3, bo3,
                                 pbuf, out);
}